// Round 1
// 1958.024 us; speedup vs baseline: 1.8218x; 1.8218x over previous
//
#include <hip/hip_runtime.h>
#include <cstdint>

typedef unsigned int u32;
typedef unsigned short u16;
typedef short bf16x8 __attribute__((ext_vector_type(8)));
typedef float f32x4 __attribute__((ext_vector_type(4)));

#define Bq 512
#define Tq 100
#define NST 200
#define NLAT 30
#define NEMB 1024
#define NACT 6

// packed weight tile offsets (tile = 16n x 32k = 512 bf16 = 1KB, B-fragment order)
#define T_LA   0      // 13 nt x 2 kt   (lat_act_W, K padded 36->64)
#define T_IH   26     // 39 nt x 7 kt   (gru_Wih rows reordered: (group g, gate) triples)
#define T_HH   299    // 39 nt x 7 kt
#define T_P1   572    // 13 nt x 7 kt   (post1_W[:, :200])
#define T_PM   663    //  2 nt x 7 kt   (post_m_W)
#define T_POST 677    // 13 nt x 32 kt  (post1_W[:, 200:], K=1024)
#define T_PR1  1093   // 13 nt x 7 kt   (prior1_W)
#define T_TOT  1184
#define NFRAG  (T_TOT * 64)

__device__ __forceinline__ u16 f2bf(float f){
  u32 x = __float_as_uint(f);
  return (u16)((x + 0x7FFFu + ((x >> 16) & 1u)) >> 16);
}
__device__ __forceinline__ float bf2f(u16 h){ return __uint_as_float(((u32)h) << 16); }

__device__ __forceinline__ float sigm(float x){ return 1.0f / (1.0f + expf(-x)); }
__device__ __forceinline__ float stdf_(float x){
  float sp = fmaxf(x, 0.f) + log1pf(expf(-fabsf(x))) + 0.1f;
  return fminf(fmaxf(sp, 1e-6f), 10.0f);
}

// raw barrier: drain LDS ops only (lgkmcnt), do NOT drain vmcnt — keeps
// global weight prefetches in flight across phase boundaries (T4 pattern).
#define BAR() do { \
  asm volatile("s_waitcnt lgkmcnt(0)" ::: "memory"); \
  __builtin_amdgcn_s_barrier(); \
  asm volatile("" ::: "memory"); \
} while (0)

// load one 7-fragment weight unit (unit index = row of 7 consecutive tiles)
#define LOAD7(dst, base, unit) do { \
  const u16* _p = (base) + ((((size_t)(unit))*7) << 9) + lane*8; \
  _Pragma("unroll") \
  for (int _k = 0; _k < 7; ++_k) dst[_k] = *(const bf16x8*)(_p + ((size_t)_k << 9)); \
} while (0)

#define CHAIN7(accv, Afr, buf) do { \
  _Pragma("unroll") \
  for (int _k = 0; _k < 7; ++_k) \
    accv = __builtin_amdgcn_mfma_f32_16x16x32_bf16(Afr[_k], buf[_k], accv, 0, 0, 0); \
} while (0)

// ---------------- kernel 1: pack weights into MFMA B-fragment tiles ----------------
__global__ __launch_bounds__(256) void prep2(
    const float* __restrict__ lat_act_W,
    const float* __restrict__ gru_Wih,
    const float* __restrict__ gru_Whh,
    const float* __restrict__ post1_W,
    const float* __restrict__ post_m_W,
    const float* __restrict__ prior1_W,
    u16* __restrict__ wbuf)
{
  int gid = blockIdx.x * 256 + threadIdx.x;
  if (gid >= NFRAG) return;
  int tile = gid >> 6, lane = gid & 63;
  int nl = lane & 15, qq = lane >> 4;
  const float* src = nullptr;
  long stride = 0; int row = 0, kbase = 0, kmax = 0, coff = 0; bool vn = false;
  if (tile < T_IH){                       // LA
    int lt = tile, nt = lt >> 1, kt = lt & 1;
    row = nt*16 + nl; vn = row < 200; kbase = kt*32 + qq*8; kmax = 36;
    src = lat_act_W; stride = 36;
  } else if (tile < T_HH){                // IH (gate-triple reordered)
    int lt = tile - T_IH, nt = lt / 7, kt = lt - nt*7;
    int g = nt / 3, gate = nt - g*3, nn = g*16 + nl;
    vn = nn < 200; row = gate*200 + nn; kbase = kt*32 + qq*8; kmax = 200;
    src = gru_Wih; stride = 200;
  } else if (tile < T_P1){                // HH
    int lt = tile - T_HH, nt = lt / 7, kt = lt - nt*7;
    int g = nt / 3, gate = nt - g*3, nn = g*16 + nl;
    vn = nn < 200; row = gate*200 + nn; kbase = kt*32 + qq*8; kmax = 200;
    src = gru_Whh; stride = 200;
  } else if (tile < T_PM){                // P1 (post1 h-part)
    int lt = tile - T_P1, nt = lt / 7, kt = lt - nt*7;
    row = nt*16 + nl; vn = row < 200; kbase = kt*32 + qq*8; kmax = 200;
    src = post1_W; stride = 1224;
  } else if (tile < T_POST){              // PM
    int lt = tile - T_PM, nt = lt / 7, kt = lt - nt*7;
    row = nt*16 + nl; vn = row < 30; kbase = kt*32 + qq*8; kmax = 200;
    src = post_m_W; stride = 200;
  } else if (tile < T_PR1){               // POST (post1 e-part, K=1024)
    int lt = tile - T_POST, nt = lt >> 5, kt = lt & 31;
    row = nt*16 + nl; vn = row < 200; kbase = kt*32 + qq*8; kmax = 1024; coff = 200;
    src = post1_W; stride = 1224;
  } else {                                // PR1
    int lt = tile - T_PR1, nt = lt / 7, kt = lt - nt*7;
    row = nt*16 + nl; vn = row < 200; kbase = kt*32 + qq*8; kmax = 200;
    src = prior1_W; stride = 200;
  }
  __align__(16) u16 ov[8];
  #pragma unroll
  for (int j = 0; j < 8; ++j){
    int k = kbase + j;
    float v = (vn && k < kmax) ? src[(size_t)row*stride + coff + k] : 0.f;
    ov[j] = f2bf(v);
  }
  *(uint4*)(wbuf + (size_t)gid*8) = *(const uint4*)ov;
}

// ---------------- kernel 2: Epost = e[:,1:] @ post1_W[:,200:].T + post1_b (bf16 out) ----------------
__global__ __launch_bounds__(256) void epost_kernel(
    const float* __restrict__ e,
    const float* __restrict__ post1_b,
    const u16* __restrict__ wbuf,
    u16* __restrict__ Epost)
{
  __shared__ __align__(16) u16 Ab[2][64][40];
  const int tid = threadIdx.x;
  const int wave = tid >> 6, lane = tid & 63, nl = lane & 15, q = lane >> 4;
  const int m0 = blockIdx.x * 64;
  const int tt = m0 >> 9;
  const int b0 = m0 & 511;
  const u16* wPOST = wbuf + (size_t)T_POST * 512;

  f32x4 zero4 = {0.f, 0.f, 0.f, 0.f};
  f32x4 acc[13];
  #pragma unroll
  for (int i = 0; i < 13; ++i) acc[i] = zero4;

  const int sr = tid >> 2;
  const int sc = (tid & 3) * 8;
  const float* esrc = e + ((size_t)(b0 + sr)*(Tq + 1) + (tt + 1))*NEMB + sc;

  {
    float4 f0 = *(const float4*)(esrc);
    float4 f1 = *(const float4*)(esrc + 4);
    bf16x8 v;
    v[0]=(short)f2bf(f0.x); v[1]=(short)f2bf(f0.y); v[2]=(short)f2bf(f0.z); v[3]=(short)f2bf(f0.w);
    v[4]=(short)f2bf(f1.x); v[5]=(short)f2bf(f1.y); v[6]=(short)f2bf(f1.z); v[7]=(short)f2bf(f1.w);
    *(bf16x8*)(&Ab[0][sr][sc]) = v;
  }
  __syncthreads();
  for (int kt = 0; kt < 32; ++kt){
    int cur = kt & 1;
    if (kt + 1 < 32){
      const float* p = esrc + (size_t)(kt + 1)*32;
      float4 f0 = *(const float4*)(p);
      float4 f1 = *(const float4*)(p + 4);
      bf16x8 v;
      v[0]=(short)f2bf(f0.x); v[1]=(short)f2bf(f0.y); v[2]=(short)f2bf(f0.z); v[3]=(short)f2bf(f0.w);
      v[4]=(short)f2bf(f1.x); v[5]=(short)f2bf(f1.y); v[6]=(short)f2bf(f1.z); v[7]=(short)f2bf(f1.w);
      *(bf16x8*)(&Ab[cur ^ 1][sr][sc]) = v;
    }
    bf16x8 afr = *(const bf16x8*)(&Ab[cur][wave*16 + nl][q*8]);
    #pragma unroll
    for (int nt = 0; nt < 13; ++nt){
      bf16x8 b = *(const bf16x8*)(wPOST + (((size_t)(nt*32 + kt)) << 9) + lane*8);
      acc[nt] = __builtin_amdgcn_mfma_f32_16x16x32_bf16(afr, b, acc[nt], 0, 0, 0);
    }
    __syncthreads();
  }
  #pragma unroll
  for (int nt = 0; nt < 13; ++nt){
    int n = nt*16 + nl;
    if (n < 200){
      float bb = post1_b[n];
      #pragma unroll
      for (int r = 0; r < 4; ++r){
        int m = m0 + wave*16 + q*4 + r;
        Epost[(size_t)m*NST + n] = f2bf(acc[nt][r] + bb);
      }
    }
  }
}

// ---------------- kernel 3: sequential MFMA core (32 blocks x 16 rows, 8 waves) ----------------
// Software-pipelined weight stream: ping-pong 7-fragment register buffers are
// threaded through LAT->GATES->P1->QM and across the step boundary, so the
// vector-memory port never drains. Barriers wait lgkmcnt only (no vmcnt(0)),
// letting prefetches cross phase boundaries. LA weights + all biases are
// register-persistent for all 100 steps; fp32 h master lives in per-lane regs.
__global__ __launch_bounds__(512, 2) void core_kernel(
    const float* __restrict__ u,
    const float* __restrict__ lat_act_b,
    const float* __restrict__ gru_bih,
    const float* __restrict__ gru_bhh,
    const float* __restrict__ post_m_b,
    const u16* __restrict__ wbuf,
    const u16* __restrict__ Epost,
    float* __restrict__ out_states,
    float* __restrict__ out_qm)
{
  __shared__ __align__(16) u16 xs[16][72];        // [ s(30) | u(6) | pad->64 ] bf16
  __shared__ __align__(16) u16 xb[16][232];       // lat output bf16, K-pad 224
  __shared__ __align__(16) u16 hb[2][16][232];    // h bf16 mirror, double-buffered
  __shared__ __align__(16) u16 zqb[16][232];      // zq bf16

  const int tid  = threadIdx.x;
  const int wave = tid >> 6;
  const int lane = tid & 63;
  const int nl   = lane & 15;
  const int q    = lane >> 4;
  const int row0 = blockIdx.x * 16;

  const u16* wLA = wbuf + (size_t)T_LA * 512;
  const u16* wIH = wbuf + (size_t)T_IH * 512;
  const u16* wHH = wbuf + (size_t)T_HH * 512;
  const u16* wP1 = wbuf + (size_t)T_P1 * 512;
  const u16* wPM = wbuf + (size_t)T_PM * 512;

  for (int i = tid; i < 16*72;  i += 512) ((u16*)xs)[i] = 0;
  for (int i = tid; i < 16*232; i += 512){
    ((u16*)xb)[i] = 0; ((u16*)hb[0])[i] = 0; ((u16*)hb[1])[i] = 0; ((u16*)zqb)[i] = 0;
  }

  const bool two  = (wave < 5);          // has a second n-tile (wave+8 < 13)
  const int  cmax = two ? 2 : 1;

  // --- register-persistent LA fragments and biases (loaded once) ---
  bf16x8 laf[2][2] = {};
  float latb_r[2] = {0.f, 0.f};
  float bih_r[2][3] = {}, bhh_r[2][3] = {};
  #pragma unroll
  for (int c = 0; c < 2; ++c){
    if (c < cmax){
      const int nt = wave + 8*c;
      #pragma unroll
      for (int kt = 0; kt < 2; ++kt)
        laf[c][kt] = *(const bf16x8*)(wLA + (((size_t)(nt*2 + kt)) << 9) + lane*8);
      const int n = nt*16 + nl;
      const bool v = (n < 200);
      latb_r[c] = v ? lat_act_b[n] : 0.f;
      #pragma unroll
      for (int gg = 0; gg < 3; ++gg){
        bih_r[c][gg] = v ? gru_bih[gg*200 + n] : 0.f;
        bhh_r[c][gg] = v ? gru_bhh[gg*200 + n] : 0.f;
      }
    }
  }
  float pmb_r = 0.f;
  { const int n2 = wave*16 + nl; if (wave < 2 && n2 < 30) pmb_r = post_m_b[n2]; }

  float hreg[2][4] = {};                 // fp32 master h (same-lane read/write)

  const int ur = tid / 6, uk = tid - ur*6;
  const bool uth = (tid < 96);
  float u_reg = uth ? u[((size_t)(row0 + ur)*Tq + 0)*NACT + uk] : 0.f;

  // prime the pipeline: GATES unit 0 (group=wave, gate=0, IH)
  bf16x8 bbA[7], bbB[7];
  LOAD7(bbA, wIH, wave*3);

  BAR();

  for (int t = 0; t < Tq; ++t){
    const int pb = t & 1;
    if (uth) xs[ur][30 + uk] = f2bf(u_reg);
    BAR();                                           // B0

    // ---- Epost prefetch for this step (consumed in P1 epilogue) ----
    u32 ep0[4], ep1[4];
    {
      const int n0 = wave*16 + nl;                   // always < 200
      const int n1 = n0 + 128;
      const u16* eb = Epost + ((size_t)t*Bq + row0 + q*4)*NST;
      #pragma unroll
      for (int r = 0; r < 4; ++r){
        ep0[r] = eb[(size_t)r*NST + n0];
        ep1[r] = (two && n1 < 200) ? (u32)eb[(size_t)r*NST + n1] : 0u;
      }
    }

    // ---- LAT: x = relu([s,a] @ Wla^T + b) — weights register-resident ----
    {
      bf16x8 a0 = *(const bf16x8*)(&xs[nl][q*8]);
      bf16x8 a1 = *(const bf16x8*)(&xs[nl][32 + q*8]);
      #pragma unroll
      for (int c = 0; c < 2; ++c){
        if (c < cmax){
          f32x4 a = {0.f, 0.f, 0.f, 0.f};
          a = __builtin_amdgcn_mfma_f32_16x16x32_bf16(a0, laf[c][0], a, 0, 0, 0);
          a = __builtin_amdgcn_mfma_f32_16x16x32_bf16(a1, laf[c][1], a, 0, 0, 0);
          const int n = (wave + 8*c)*16 + nl;
          if (n < 200){
            #pragma unroll
            for (int r = 0; r < 4; ++r)
              xb[q*4 + r][n] = f2bf(fmaxf(a[r] + latb_r[c], 0.f));
          }
        }
      }
    }
    BAR();                                           // B1

    // ---- GATES: GRU with pipelined weight units ----
    {
      bf16x8 ax[7], ah[7];
      #pragma unroll
      for (int kt = 0; kt < 7; ++kt){
        ax[kt] = *(const bf16x8*)(&xb[nl][kt*32 + q*8]);
        ah[kt] = *(const bf16x8*)(&hb[pb][nl][kt*32 + q*8]);
      }
      if (uth && t + 1 < Tq) u_reg = u[((size_t)(row0 + ur)*Tq + (t + 1))*NACT + uk];

      #pragma unroll
      for (int c = 0; c < 2; ++c){
        if (c < cmax){
          const int g  = wave + 8*c;
          const int gu = g*3;
          f32x4 acc0  = {0.f,0.f,0.f,0.f};           // r gate: ih+hh merged
          f32x4 acc1  = {0.f,0.f,0.f,0.f};           // z gate: ih+hh merged
          f32x4 acc2i = {0.f,0.f,0.f,0.f};           // n gate: ih part
          f32x4 acc2h = {0.f,0.f,0.f,0.f};           // n gate: hh part
          LOAD7(bbB, wHH, gu + 0);
          CHAIN7(acc0, ax, bbA);                     // bbA = (g,0,ih)
          LOAD7(bbA, wIH, gu + 1);
          CHAIN7(acc0, ah, bbB);                     // bbB = (g,0,hh)
          LOAD7(bbB, wHH, gu + 1);
          CHAIN7(acc1, ax, bbA);                     // bbA = (g,1,ih)
          LOAD7(bbA, wIH, gu + 2);
          CHAIN7(acc1, ah, bbB);                     // bbB = (g,1,hh)
          LOAD7(bbB, wHH, gu + 2);
          CHAIN7(acc2i, ax, bbA);                    // bbA = (g,2,ih)
          if (c == 0 && cmax == 2) LOAD7(bbA, wIH, (g + 8)*3);   // next c unit 0
          else                     LOAD7(bbA, wP1, wave);        // P1 nt0 unit
          CHAIN7(acc2h, ah, bbB);                    // bbB = (g,2,hh)

          const int n = g*16 + nl;
          if (n < 200){
            #pragma unroll
            for (int r = 0; r < 4; ++r){
              const int m = q*4 + r;
              float rg = sigm(acc0[r] + bih_r[c][0] + bhh_r[c][0]);
              float zg = sigm(acc1[r] + bih_r[c][1] + bhh_r[c][1]);
              float ng = tanhf(acc2i[r] + bih_r[c][2] + rg*(acc2h[r] + bhh_r[c][2]));
              float hn = (1.f - zg)*ng + zg*hreg[c][r];
              hreg[c][r] = hn;
              hb[pb ^ 1][m][n] = f2bf(hn);
              out_states[((size_t)t*Bq + row0 + m)*NST + n] = hn;
            }
          }
        }
      }
    }
    BAR();                                           // B2

    // ---- P1: zq = relu(h_new @ Wp1^T + Epost) ----
    {
      bf16x8 ah2[7];
      #pragma unroll
      for (int kt = 0; kt < 7; ++kt)
        ah2[kt] = *(const bf16x8*)(&hb[pb ^ 1][nl][kt*32 + q*8]);
      f32x4 aP0 = {0.f,0.f,0.f,0.f}, aP1 = {0.f,0.f,0.f,0.f};
      if (two) LOAD7(bbB, wP1, wave + 8);
      CHAIN7(aP0, ah2, bbA);                         // bbA = P1 nt0
      if (two){
        if (wave < 2) LOAD7(bbA, wPM, wave);         // QM unit
        else          LOAD7(bbA, wIH, wave*3);       // next-step GATES unit 0
        CHAIN7(aP1, ah2, bbB);                       // bbB = P1 nt1
      } else {
        LOAD7(bbA, wIH, wave*3);                     // next-step GATES unit 0
      }
      {
        const int n0 = wave*16 + nl;
        #pragma unroll
        for (int r = 0; r < 4; ++r)
          zqb[q*4 + r][n0] = f2bf(fmaxf(aP0[r] + bf2f((u16)ep0[r]), 0.f));
        if (two){
          const int n1 = n0 + 128;
          if (n1 < 200){
            #pragma unroll
            for (int r = 0; r < 4; ++r)
              zqb[q*4 + r][n1] = f2bf(fmaxf(aP1[r] + bf2f((u16)ep1[r]), 0.f));
          }
        }
      }
    }
    BAR();                                           // B3

    // ---- QM: qm = zq @ Wpm^T + b (feeds next-step s) ----
    if (wave < 2){
      bf16x8 az[7];
      #pragma unroll
      for (int kt = 0; kt < 7; ++kt)
        az[kt] = *(const bf16x8*)(&zqb[nl][kt*32 + q*8]);
      f32x4 aQ = {0.f,0.f,0.f,0.f};
      CHAIN7(aQ, az, bbA);                           // bbA = QM unit
      const int n = wave*16 + nl;
      if (n < 30){
        #pragma unroll
        for (int r = 0; r < 4; ++r){
          const int m = q*4 + r;
          float v = aQ[r] + pmb_r;
          out_qm[((size_t)t*Bq + row0 + m)*NLAT + n] = v;
          xs[m][n] = f2bf(v);
        }
      }
      LOAD7(bbA, wIH, wave*3);                       // next-step GATES unit 0
    }
    // loop back; B0 of next iteration synchronizes
  }
}

// ---------------- kernel 4: prior branch + qs head ----------------
__global__ __launch_bounds__(256) void phasec_kernel(
    const float* __restrict__ states,
    const u16* __restrict__ Epost,
    const u16* __restrict__ wbuf,
    const float* __restrict__ prior1_b,
    const float* __restrict__ prior_m_W, const float* __restrict__ prior_m_b,
    const float* __restrict__ prior_s_W, const float* __restrict__ prior_s_b,
    const float* __restrict__ post_s_W,  const float* __restrict__ post_s_b,
    float* __restrict__ pm, float* __restrict__ ps, float* __restrict__ qs)
{
  __shared__ __align__(16) u16 stb[32][232];
  __shared__ float zp[32][208];
  __shared__ float zqf[32][208];
  const int tid = threadIdx.x, wave = tid >> 6, lane = tid & 63, nl = lane & 15, q = lane >> 4;
  const size_t m0 = (size_t)blockIdx.x * 32;
  const u16* wP1  = wbuf + (size_t)T_P1 * 512;
  const u16* wPR1 = wbuf + (size_t)T_PR1 * 512;

  for (int i = tid; i < 32*200; i += 256){
    int r = i / 200, c = i - r*200;
    stb[r][c] = f2bf(states[(m0 + r)*NST + c]);
  }
  for (int i = tid; i < 32*32; i += 256){
    int r = i >> 5, c = i & 31;
    stb[r][200 + c] = 0;
  }
  __syncthreads();

  {
    const int rowb = (wave & 1) * 16;
    const bool doZQ = (wave >= 2);
    const u16* wmat = doZQ ? wP1 : wPR1;
    bf16x8 a7[7];
    #pragma unroll
    for (int kt = 0; kt < 7; ++kt)
      a7[kt] = *(const bf16x8*)(&stb[rowb + nl][kt*32 + q*8]);
    for (int nt = 0; nt < 13; ++nt){
      f32x4 a = {0.f, 0.f, 0.f, 0.f};
      #pragma unroll
      for (int kt = 0; kt < 7; ++kt){
        bf16x8 b = *(const bf16x8*)(wmat + (((size_t)(nt*7 + kt)) << 9) + lane*8);
        a = __builtin_amdgcn_mfma_f32_16x16x32_bf16(a7[kt], b, a, 0, 0, 0);
      }
      int n = nt*16 + nl;
      if (n < 200){
        #pragma unroll
        for (int r = 0; r < 4; ++r){
          int m = rowb + q*4 + r;
          if (doZQ){
            float v = a[r] + bf2f(Epost[(m0 + m)*NST + n]);
            zqf[m][n] = fmaxf(v, 0.f);
          } else {
            float v = a[r] + prior1_b[n];
            zp[m][n] = fmaxf(v, 0.f);
          }
        }
      }
    }
  }
  __syncthreads();

  for (int i = tid; i < 32*90; i += 256){
    int r = i / 90, rem = i - r*90;
    int head = rem / 30, l = rem - head*30;
    const float* wrow = (head == 0 ? prior_m_W : head == 1 ? prior_s_W : post_s_W) + (size_t)l*NST;
    const float* vec = (head == 2) ? &zqf[r][0] : &zp[r][0];
    float acc = 0.f;
    #pragma unroll 10
    for (int c = 0; c < 50; ++c){
      float4 wv = *(const float4*)(wrow + c*4);
      acc = fmaf(wv.x, vec[c*4 + 0], acc);
      acc = fmaf(wv.y, vec[c*4 + 1], acc);
      acc = fmaf(wv.z, vec[c*4 + 2], acc);
      acc = fmaf(wv.w, vec[c*4 + 3], acc);
    }
    float bias = (head == 0 ? prior_m_b : head == 1 ? prior_s_b : post_s_b)[l];
    float v = acc + bias;
    if (head) v = stdf_(v);
    float* o = head == 0 ? pm : head == 1 ? ps : qs;
    o[(m0 + r)*NLAT + l] = v;
  }
}

// ---------------- launcher ----------------
extern "C" void kernel_launch(void* const* d_in, const int* in_sizes, int n_in,
                              void* d_out, int out_size, void* d_ws, size_t ws_size,
                              hipStream_t stream)
{
  const float* e         = (const float*)d_in[0];
  const float* u         = (const float*)d_in[1];
  const float* lat_act_W = (const float*)d_in[2];
  const float* lat_act_b = (const float*)d_in[3];
  const float* gru_Wih   = (const float*)d_in[4];
  const float* gru_Whh   = (const float*)d_in[5];
  const float* gru_bih   = (const float*)d_in[6];
  const float* gru_bhh   = (const float*)d_in[7];
  const float* prior1_W  = (const float*)d_in[8];
  const float* prior1_b  = (const float*)d_in[9];
  const float* prior_m_W = (const float*)d_in[10];
  const float* prior_m_b = (const float*)d_in[11];
  const float* prior_s_W = (const float*)d_in[12];
  const float* prior_s_b = (const float*)d_in[13];
  const float* post1_W   = (const float*)d_in[14];
  const float* post1_b   = (const float*)d_in[15];
  const float* post_m_W  = (const float*)d_in[16];
  const float* post_m_b  = (const float*)d_in[17];
  const float* post_s_W  = (const float*)d_in[18];
  const float* post_s_b  = (const float*)d_in[19];

  float* out    = (float*)d_out;
  float* states = out;                       // [100][512][200]
  float* pm     = out + 10240000;
  float* ps     = out + 11776000;
  float* qm     = out + 13312000;
  float* qs     = out + 14848000;

  u16* Epost = (u16*)d_ws;                               // 10,240,000 bf16 = 20.48 MB
  u16* wbuf  = (u16*)((char*)d_ws + 20480000);           // 1.21 MB packed weights

  hipLaunchKernelGGL(prep2, dim3((NFRAG + 255) / 256), dim3(256), 0, stream,
                     lat_act_W, gru_Wih, gru_Whh, post1_W, post_m_W, prior1_W, wbuf);

  hipLaunchKernelGGL(epost_kernel, dim3(800), dim3(256), 0, stream,
                     e, post1_b, wbuf, Epost);

  hipLaunchKernelGGL(core_kernel, dim3(32), dim3(512), 0, stream,
                     u, lat_act_b, gru_bih, gru_bhh, post_m_b, wbuf, Epost, states, qm);

  hipLaunchKernelGGL(phasec_kernel, dim3(1600), dim3(256), 0, stream,
                     states, Epost, wbuf, prior1_b,
                     prior_m_W, prior_m_b, prior_s_W, prior_s_b,
                     post_s_W, post_s_b, pm, ps, qs);
}

// Round 2
// 1949.222 us; speedup vs baseline: 1.8300x; 1.0045x over previous
//
#include <hip/hip_runtime.h>
#include <cstdint>

typedef unsigned int u32;
typedef unsigned short u16;
typedef short bf16x8 __attribute__((ext_vector_type(8)));
typedef float f32x4 __attribute__((ext_vector_type(4)));

#define Bq 512
#define Tq 100
#define NST 200
#define NLAT 30
#define NEMB 1024
#define NACT 6

// packed weight tile offsets (tile = 16n x 32k = 512 bf16 = 1KB, B-fragment order)
#define T_LA   0      // 13 nt x 2 kt   (lat_act_W, K padded 36->64)
#define T_IH   26     // 39 nt x 7 kt   (gru_Wih rows reordered: (group g, gate) triples)
#define T_HH   299    // 39 nt x 7 kt
#define T_P1   572    // 13 nt x 7 kt   (post1_W[:, :200])
#define T_PM   663    //  2 nt x 7 kt   (post_m_W)
#define T_POST 677    // 13 nt x 32 kt  (post1_W[:, 200:], K=1024)
#define T_PR1  1093   // 13 nt x 7 kt   (prior1_W)
#define T_TOT  1184
#define NFRAG  (T_TOT * 64)

__device__ __forceinline__ u16 f2bf(float f){
  u32 x = __float_as_uint(f);
  return (u16)((x + 0x7FFFu + ((x >> 16) & 1u)) >> 16);
}
__device__ __forceinline__ float bf2f(u16 h){ return __uint_as_float(((u32)h) << 16); }

// hardware transcendentals (~1 ulp; saturate correctly at +-inf)
__device__ __forceinline__ float fexp2(float x){ float r; asm("v_exp_f32 %0, %1" : "=v"(r) : "v"(x)); return r; }
__device__ __forceinline__ float frcp (float x){ float r; asm("v_rcp_f32 %0, %1" : "=v"(r) : "v"(x)); return r; }
#define LOG2E 1.44269504f
__device__ __forceinline__ float fsigm(float x){ return frcp(1.0f + fexp2(-LOG2E * x)); }
__device__ __forceinline__ float ftanh(float x){ return 1.0f - 2.0f * frcp(1.0f + fexp2(2.0f * LOG2E * x)); }

__device__ __forceinline__ float stdf_(float x){
  float sp = fmaxf(x, 0.f) + log1pf(expf(-fabsf(x))) + 0.1f;
  return fminf(fmaxf(sp, 1e-6f), 10.0f);
}

// raw barrier: drain LDS ops only (lgkmcnt), do NOT drain vmcnt — keeps
// global weight prefetches in flight across phase boundaries (T4 pattern).
#define BAR() do { \
  asm volatile("s_waitcnt lgkmcnt(0)" ::: "memory"); \
  __builtin_amdgcn_s_barrier(); \
  asm volatile("" ::: "memory"); \
} while (0)

// load one 7-fragment weight unit (unit index = row of 7 consecutive tiles)
#define LOAD7(dst, base, unit) do { \
  const u16* _p = (base) + ((((size_t)(unit))*7) << 9) + lane*8; \
  _Pragma("unroll") \
  for (int _k = 0; _k < 7; ++_k) dst[_k] = *(const bf16x8*)(_p + ((size_t)_k << 9)); \
} while (0)

#define CHAIN7(accv, Afr, buf) do { \
  _Pragma("unroll") \
  for (int _k = 0; _k < 7; ++_k) \
    accv = __builtin_amdgcn_mfma_f32_16x16x32_bf16(Afr[_k], buf[_k], accv, 0, 0, 0); \
} while (0)

// ---------------- kernel 1: pack weights into MFMA B-fragment tiles ----------------
__global__ __launch_bounds__(256) void prep2(
    const float* __restrict__ lat_act_W,
    const float* __restrict__ gru_Wih,
    const float* __restrict__ gru_Whh,
    const float* __restrict__ post1_W,
    const float* __restrict__ post_m_W,
    const float* __restrict__ prior1_W,
    u16* __restrict__ wbuf)
{
  int gid = blockIdx.x * 256 + threadIdx.x;
  if (gid >= NFRAG) return;
  int tile = gid >> 6, lane = gid & 63;
  int nl = lane & 15, qq = lane >> 4;
  const float* src = nullptr;
  long stride = 0; int row = 0, kbase = 0, kmax = 0, coff = 0; bool vn = false;
  if (tile < T_IH){                       // LA
    int lt = tile, nt = lt >> 1, kt = lt & 1;
    row = nt*16 + nl; vn = row < 200; kbase = kt*32 + qq*8; kmax = 36;
    src = lat_act_W; stride = 36;
  } else if (tile < T_HH){                // IH (gate-triple reordered)
    int lt = tile - T_IH, nt = lt / 7, kt = lt - nt*7;
    int g = nt / 3, gate = nt - g*3, nn = g*16 + nl;
    vn = nn < 200; row = gate*200 + nn; kbase = kt*32 + qq*8; kmax = 200;
    src = gru_Wih; stride = 200;
  } else if (tile < T_P1){                // HH
    int lt = tile - T_HH, nt = lt / 7, kt = lt - nt*7;
    int g = nt / 3, gate = nt - g*3, nn = g*16 + nl;
    vn = nn < 200; row = gate*200 + nn; kbase = kt*32 + qq*8; kmax = 200;
    src = gru_Whh; stride = 200;
  } else if (tile < T_PM){                // P1 (post1 h-part)
    int lt = tile - T_P1, nt = lt / 7, kt = lt - nt*7;
    row = nt*16 + nl; vn = row < 200; kbase = kt*32 + qq*8; kmax = 200;
    src = post1_W; stride = 1224;
  } else if (tile < T_POST){              // PM
    int lt = tile - T_PM, nt = lt / 7, kt = lt - nt*7;
    row = nt*16 + nl; vn = row < 30; kbase = kt*32 + qq*8; kmax = 200;
    src = post_m_W; stride = 200;
  } else if (tile < T_PR1){               // POST (post1 e-part, K=1024)
    int lt = tile - T_POST, nt = lt >> 5, kt = lt & 31;
    row = nt*16 + nl; vn = row < 200; kbase = kt*32 + qq*8; kmax = 1024; coff = 200;
    src = post1_W; stride = 1224;
  } else {                                // PR1
    int lt = tile - T_PR1, nt = lt / 7, kt = lt - nt*7;
    row = nt*16 + nl; vn = row < 200; kbase = kt*32 + qq*8; kmax = 200;
    src = prior1_W; stride = 200;
  }
  __align__(16) u16 ov[8];
  #pragma unroll
  for (int j = 0; j < 8; ++j){
    int k = kbase + j;
    float v = (vn && k < kmax) ? src[(size_t)row*stride + coff + k] : 0.f;
    ov[j] = f2bf(v);
  }
  *(uint4*)(wbuf + (size_t)gid*8) = *(const uint4*)ov;
}

// ---------------- kernel 2: Epost = e[:,1:] @ post1_W[:,200:].T + post1_b ----------------
// Barrier-free: each lane reads its A-fragment (8 consecutive fp32) straight
// from e; no LDS staging at all, so the 32 kt-iterations pipeline freely and
// block-level TLP (no LDS, ~96 VGPR) hides the B-fragment L2 latency.
__global__ __launch_bounds__(256) void epost_kernel(
    const float* __restrict__ e,
    const float* __restrict__ post1_b,
    const u16* __restrict__ wbuf,
    u16* __restrict__ Epost)
{
  const int tid = threadIdx.x;
  const int wave = tid >> 6, lane = tid & 63, nl = lane & 15, q = lane >> 4;
  const int m0 = blockIdx.x * 64;
  const int tt = m0 >> 9;
  const int b0 = (m0 & 511) + wave*16;
  const u16* wPOST = wbuf + (size_t)T_POST * 512 + lane*8;

  f32x4 acc[13];
  #pragma unroll
  for (int i = 0; i < 13; ++i) acc[i] = (f32x4){0.f,0.f,0.f,0.f};

  const float* arow = e + ((size_t)(b0 + nl)*(Tq + 1) + (tt + 1))*NEMB + q*8;

  for (int kt = 0; kt < 32; ++kt){
    float4 f0 = *(const float4*)(arow + (size_t)kt*32);
    float4 f1 = *(const float4*)(arow + (size_t)kt*32 + 4);
    bf16x8 afr;
    afr[0]=(short)f2bf(f0.x); afr[1]=(short)f2bf(f0.y); afr[2]=(short)f2bf(f0.z); afr[3]=(short)f2bf(f0.w);
    afr[4]=(short)f2bf(f1.x); afr[5]=(short)f2bf(f1.y); afr[6]=(short)f2bf(f1.z); afr[7]=(short)f2bf(f1.w);
    #pragma unroll
    for (int nt = 0; nt < 13; ++nt){
      bf16x8 b = *(const bf16x8*)(wPOST + (((size_t)(nt*32 + kt)) << 9));
      acc[nt] = __builtin_amdgcn_mfma_f32_16x16x32_bf16(afr, b, acc[nt], 0, 0, 0);
    }
  }
  #pragma unroll
  for (int nt = 0; nt < 13; ++nt){
    int n = nt*16 + nl;
    if (n < 200){
      float bb = post1_b[n];
      #pragma unroll
      for (int r = 0; r < 4; ++r){
        int m = m0 + wave*16 + q*4 + r;
        Epost[(size_t)m*NST + n] = f2bf(acc[nt][r] + bb);
      }
    }
  }
}

// ---------------- kernel 3: sequential MFMA core (32 blocks x 16 rows, 8 waves) ----------------
// Depth-3 weight ring (b0/b1/b2, strict mod-3 in GATES; hand-assigned tail per
// wave class keeps the loop-top invariant {b0=IH(g0,0), b1=HH(g0,0)}). Fast
// hardware sigmoid/tanh. Biases + LA weights + fp32 h master all in registers.
__global__ __launch_bounds__(512, 2) void core_kernel(
    const float* __restrict__ u,
    const float* __restrict__ lat_act_b,
    const float* __restrict__ gru_bih,
    const float* __restrict__ gru_bhh,
    const float* __restrict__ post_m_b,
    const u16* __restrict__ wbuf,
    const u16* __restrict__ Epost,
    float* __restrict__ out_states,
    float* __restrict__ out_qm)
{
  __shared__ __align__(16) u16 xs[16][72];        // [ s(30) | u(6) | pad->64 ] bf16
  __shared__ __align__(16) u16 xb[16][232];       // lat output bf16, K-pad 224
  __shared__ __align__(16) u16 hb[2][16][232];    // h bf16 mirror, double-buffered
  __shared__ __align__(16) u16 zqb[16][232];      // zq bf16

  const int tid  = threadIdx.x;
  const int wave = tid >> 6;
  const int lane = tid & 63;
  const int nl   = lane & 15;
  const int q    = lane >> 4;
  const int row0 = blockIdx.x * 16;

  const u16* wLA = wbuf + (size_t)T_LA * 512;
  const u16* wIH = wbuf + (size_t)T_IH * 512;
  const u16* wHH = wbuf + (size_t)T_HH * 512;
  const u16* wP1 = wbuf + (size_t)T_P1 * 512;
  const u16* wPM = wbuf + (size_t)T_PM * 512;

  const bool two  = (wave < 5);          // has a second n-tile (wave+8 < 13)
  const int  cmax = two ? 2 : 1;

  // prime the ring: next-GATES unit 0 (IH + HH) in flight before the loop
  bf16x8 b0[7], b1[7], b2[7];
  LOAD7(b0, wIH, wave*3);
  LOAD7(b1, wHH, wave*3);

  for (int i = tid; i < 16*72;  i += 512) ((u16*)xs)[i] = 0;
  for (int i = tid; i < 16*232; i += 512){
    ((u16*)xb)[i] = 0; ((u16*)hb[0])[i] = 0; ((u16*)hb[1])[i] = 0; ((u16*)zqb)[i] = 0;
  }

  // --- register-persistent LA fragments and biases (loaded once) ---
  bf16x8 laf[2][2] = {};
  float latb_r[2] = {0.f, 0.f};
  float brz_r[2][2] = {};                // bih+bhh pre-summed, gates r,z
  float bin_r[2] = {}, bhn_r[2] = {};    // n-gate parts (kept separate)
  #pragma unroll
  for (int c = 0; c < 2; ++c){
    if (c < cmax){
      const int nt = wave + 8*c;
      #pragma unroll
      for (int kt = 0; kt < 2; ++kt)
        laf[c][kt] = *(const bf16x8*)(wLA + (((size_t)(nt*2 + kt)) << 9) + lane*8);
      const int n = nt*16 + nl;
      const bool v = (n < 200);
      latb_r[c] = v ? lat_act_b[n] : 0.f;
      if (v){
        brz_r[c][0] = gru_bih[n]       + gru_bhh[n];
        brz_r[c][1] = gru_bih[200 + n] + gru_bhh[200 + n];
        bin_r[c]    = gru_bih[400 + n];
        bhn_r[c]    = gru_bhh[400 + n];
      }
    }
  }
  float pmb_r = 0.f;
  { const int n2 = wave*16 + nl; if (wave < 2 && n2 < 30) pmb_r = post_m_b[n2]; }

  float hreg[2][4] = {};                 // fp32 master h (same-lane read/write)

  const int ur = tid / 6, uk = tid - ur*6;
  const bool uth = (tid < 96);
  float u_reg = uth ? u[((size_t)(row0 + ur)*Tq + 0)*NACT + uk] : 0.f;

  BAR();

  for (int t = 0; t < Tq; ++t){
    const int pb = t & 1;
    if (uth) xs[ur][30 + uk] = f2bf(u_reg);
    BAR();                                           // B0

    // ---- Epost prefetch for this step (consumed in P1 epilogue) ----
    u32 ep0[4], ep1[4];
    {
      const int n0 = wave*16 + nl;                   // always < 200
      const int n1 = n0 + 128;
      const u16* eb = Epost + ((size_t)t*Bq + row0 + q*4)*NST;
      #pragma unroll
      for (int r = 0; r < 4; ++r){
        ep0[r] = eb[(size_t)r*NST + n0];
        ep1[r] = (two && n1 < 200) ? (u32)eb[(size_t)r*NST + n1] : 0u;
      }
    }

    // ---- read ah (hb[pb] is stable since B2 of the previous step) ----
    bf16x8 ah[7];
    #pragma unroll
    for (int kt = 0; kt < 7; ++kt)
      ah[kt] = *(const bf16x8*)(&hb[pb][nl][kt*32 + q*8]);

    // ---- LAT: x = relu([s,a] @ Wla^T + b) — weights register-resident ----
    {
      bf16x8 a0 = *(const bf16x8*)(&xs[nl][q*8]);
      bf16x8 a1 = *(const bf16x8*)(&xs[nl][32 + q*8]);
      #pragma unroll
      for (int c = 0; c < 2; ++c){
        if (c < cmax){
          f32x4 a = {0.f, 0.f, 0.f, 0.f};
          a = __builtin_amdgcn_mfma_f32_16x16x32_bf16(a0, laf[c][0], a, 0, 0, 0);
          a = __builtin_amdgcn_mfma_f32_16x16x32_bf16(a1, laf[c][1], a, 0, 0, 0);
          const int n = (wave + 8*c)*16 + nl;
          if (n < 200){
            #pragma unroll
            for (int r = 0; r < 4; ++r)
              xb[q*4 + r][n] = f2bf(fmaxf(a[r] + latb_r[c], 0.f));
          }
        }
      }
    }
    BAR();                                           // B1

    // ---- GATES: mod-3 ring, 2-unit lookahead ----
    {
      bf16x8 ax[7];
      #pragma unroll
      for (int kt = 0; kt < 7; ++kt)
        ax[kt] = *(const bf16x8*)(&xb[nl][kt*32 + q*8]);
      if (uth && t + 1 < Tq) u_reg = u[((size_t)(row0 + ur)*Tq + (t + 1))*NACT + uk];

      float* os = out_states + ((size_t)t*Bq + row0)*NST;

      #pragma unroll
      for (int c = 0; c < 2; ++c){
        if (c < cmax){
          const int g  = wave + 8*c;
          const int gu = g*3;
          f32x4 acc0  = {0.f,0.f,0.f,0.f};           // r gate (ih+hh merged)
          f32x4 acc1  = {0.f,0.f,0.f,0.f};           // z gate (ih+hh merged)
          f32x4 acc2i = {0.f,0.f,0.f,0.f};           // n gate ih
          f32x4 acc2h = {0.f,0.f,0.f,0.f};           // n gate hh
          // slot0: entry invariant b0=IH(gu), b1=HH(gu)
          LOAD7(b2, wIH, gu + 1);  CHAIN7(acc0, ax, b0);
          LOAD7(b0, wHH, gu + 1);  CHAIN7(acc0, ah, b1);
          LOAD7(b1, wIH, gu + 2);  CHAIN7(acc1, ax, b2);
          LOAD7(b2, wHH, gu + 2);  CHAIN7(acc1, ah, b0);
          if (c == 0 && two) { LOAD7(b0, wIH, (wave + 8)*3); }
          else               { LOAD7(b0, wP1, wave); }
          CHAIN7(acc2i, ax, b1);
          if (c == 0 && two)      { LOAD7(b1, wHH, (wave + 8)*3); }
          else if (two)           { LOAD7(b1, wP1, wave + 8); }
          CHAIN7(acc2h, ah, b2);

          const int n = g*16 + nl;
          if (n < 200){
            #pragma unroll
            for (int r = 0; r < 4; ++r){
              const int m = q*4 + r;
              float rg = fsigm(acc0[r] + brz_r[c][0]);
              float zg = fsigm(acc1[r] + brz_r[c][1]);
              float ng = ftanh(acc2i[r] + bin_r[c] + rg*(acc2h[r] + bhn_r[c]));
              float hn = (1.f - zg)*ng + zg*hreg[c][r];
              hreg[c][r] = hn;
              hb[pb ^ 1][m][n] = f2bf(hn);
              os[(size_t)m*NST + n] = hn;
            }
          }
        }
      }
    }
    BAR();                                           // B2

    // ---- P1: zq = relu(h_new @ Wp1^T + Epost); tail keeps ring invariant ----
    {
      bf16x8 ah2[7];
      #pragma unroll
      for (int kt = 0; kt < 7; ++kt)
        ah2[kt] = *(const bf16x8*)(&hb[pb ^ 1][nl][kt*32 + q*8]);
      f32x4 aP0 = {0.f,0.f,0.f,0.f}, aP1 = {0.f,0.f,0.f,0.f};
      if (wave < 2) { LOAD7(b2, wPM, wave); }        // QM unit, consumed after B3
      CHAIN7(aP0, ah2, b0);                          // b0 = P1(wave)
      LOAD7(b0, wIH, wave*3);                        // next-step IH(g0,0)
      if (two) { CHAIN7(aP1, ah2, b1); }             // b1 = P1(wave+8)
      LOAD7(b1, wHH, wave*3);                        // next-step HH(g0,0)
      {
        const int n0 = wave*16 + nl;
        #pragma unroll
        for (int r = 0; r < 4; ++r)
          zqb[q*4 + r][n0] = f2bf(fmaxf(aP0[r] + bf2f((u16)ep0[r]), 0.f));
        if (two){
          const int n1 = n0 + 128;
          if (n1 < 200){
            #pragma unroll
            for (int r = 0; r < 4; ++r)
              zqb[q*4 + r][n1] = f2bf(fmaxf(aP1[r] + bf2f((u16)ep1[r]), 0.f));
          }
        }
      }
    }
    BAR();                                           // B3

    // ---- QM: qm = zq @ Wpm^T + b (feeds next-step s) ----
    if (wave < 2){
      bf16x8 az[7];
      #pragma unroll
      for (int kt = 0; kt < 7; ++kt)
        az[kt] = *(const bf16x8*)(&zqb[nl][kt*32 + q*8]);
      f32x4 aQ = {0.f,0.f,0.f,0.f};
      CHAIN7(aQ, az, b2);                            // b2 = QM unit
      const int n = wave*16 + nl;
      if (n < 30){
        float* oq = out_qm + ((size_t)t*Bq + row0)*NLAT;
        #pragma unroll
        for (int r = 0; r < 4; ++r){
          const int m = q*4 + r;
          float v = aQ[r] + pmb_r;
          oq[(size_t)m*NLAT + n] = v;
          xs[m][n] = f2bf(v);
        }
      }
    }
    // loop back; B0 of next iteration synchronizes
  }
}

// ---------------- kernel 4: prior branch + qs head ----------------
__global__ __launch_bounds__(256) void phasec_kernel(
    const float* __restrict__ states,
    const u16* __restrict__ Epost,
    const u16* __restrict__ wbuf,
    const float* __restrict__ prior1_b,
    const float* __restrict__ prior_m_W, const float* __restrict__ prior_m_b,
    const float* __restrict__ prior_s_W, const float* __restrict__ prior_s_b,
    const float* __restrict__ post_s_W,  const float* __restrict__ post_s_b,
    float* __restrict__ pm, float* __restrict__ ps, float* __restrict__ qs)
{
  __shared__ __align__(16) u16 stb[32][232];
  __shared__ float zp[32][208];
  __shared__ float zqf[32][208];
  __shared__ float hw[90][200];           // staged head weights (coalesced once)
  const int tid = threadIdx.x, wave = tid >> 6, lane = tid & 63, nl = lane & 15, q = lane >> 4;
  const size_t m0 = (size_t)blockIdx.x * 32;
  const u16* wP1  = wbuf + (size_t)T_P1 * 512;
  const u16* wPR1 = wbuf + (size_t)T_PR1 * 512;

  for (int i = tid; i < 32*200; i += 256){
    int r = i / 200, c = i - r*200;
    stb[r][c] = f2bf(states[(m0 + r)*NST + c]);
  }
  for (int i = tid; i < 32*32; i += 256){
    int r = i >> 5, c = i & 31;
    stb[r][200 + c] = 0;
  }
  // stage head weights: hw[head*30+l][c]
  for (int i = tid; i < 90*200; i += 256){
    int hl = i / 200, c = i - hl*200;
    const float* src = (hl < 30) ? prior_m_W : (hl < 60) ? prior_s_W : post_s_W;
    int l = (hl < 30) ? hl : (hl < 60) ? hl - 30 : hl - 60;
    ((float*)hw)[i] = src[(size_t)l*NST + c];
  }
  __syncthreads();

  {
    const int rowb = (wave & 1) * 16;
    const bool doZQ = (wave >= 2);
    const u16* wmat = doZQ ? wP1 : wPR1;
    bf16x8 a7[7];
    #pragma unroll
    for (int kt = 0; kt < 7; ++kt)
      a7[kt] = *(const bf16x8*)(&stb[rowb + nl][kt*32 + q*8]);
    for (int nt = 0; nt < 13; ++nt){
      f32x4 a = {0.f, 0.f, 0.f, 0.f};
      #pragma unroll
      for (int kt = 0; kt < 7; ++kt){
        bf16x8 b = *(const bf16x8*)(wmat + (((size_t)(nt*7 + kt)) << 9) + lane*8);
        a = __builtin_amdgcn_mfma_f32_16x16x32_bf16(a7[kt], b, a, 0, 0, 0);
      }
      int n = nt*16 + nl;
      if (n < 200){
        #pragma unroll
        for (int r = 0; r < 4; ++r){
          int m = rowb + q*4 + r;
          if (doZQ){
            float v = a[r] + bf2f(Epost[(m0 + m)*NST + n]);
            zqf[m][n] = fmaxf(v, 0.f);
          } else {
            float v = a[r] + prior1_b[n];
            zp[m][n] = fmaxf(v, 0.f);
          }
        }
      }
    }
  }
  __syncthreads();

  for (int i = tid; i < 32*90; i += 256){
    int r = i / 90, rem = i - r*90;
    int head = rem / 30, l = rem - head*30;
    const float* wrow = &hw[head*30 + l][0];
    const float* vec = (head == 2) ? &zqf[r][0] : &zp[r][0];
    float acc = 0.f;
    #pragma unroll 10
    for (int c = 0; c < 50; ++c){
      acc = fmaf(wrow[c*4 + 0], vec[c*4 + 0], acc);
      acc = fmaf(wrow[c*4 + 1], vec[c*4 + 1], acc);
      acc = fmaf(wrow[c*4 + 2], vec[c*4 + 2], acc);
      acc = fmaf(wrow[c*4 + 3], vec[c*4 + 3], acc);
    }
    float bias = (head == 0 ? prior_m_b : head == 1 ? prior_s_b : post_s_b)[l];
    float v = acc + bias;
    if (head) v = stdf_(v);
    float* o = head == 0 ? pm : head == 1 ? ps : qs;
    o[(m0 + r)*NLAT + l] = v;
  }
}

// ---------------- launcher ----------------
extern "C" void kernel_launch(void* const* d_in, const int* in_sizes, int n_in,
                              void* d_out, int out_size, void* d_ws, size_t ws_size,
                              hipStream_t stream)
{
  const float* e         = (const float*)d_in[0];
  const float* u         = (const float*)d_in[1];
  const float* lat_act_W = (const float*)d_in[2];
  const float* lat_act_b = (const float*)d_in[3];
  const float* gru_Wih   = (const float*)d_in[4];
  const float* gru_Whh   = (const float*)d_in[5];
  const float* gru_bih   = (const float*)d_in[6];
  const float* gru_bhh   = (const float*)d_in[7];
  const float* prior1_W  = (const float*)d_in[8];
  const float* prior1_b  = (const float*)d_in[9];
  const float* prior_m_W = (const float*)d_in[10];
  const float* prior_m_b = (const float*)d_in[11];
  const float* prior_s_W = (const float*)d_in[12];
  const float* prior_s_b = (const float*)d_in[13];
  const float* post1_W   = (const float*)d_in[14];
  const float* post1_b   = (const float*)d_in[15];
  const float* post_m_W  = (const float*)d_in[16];
  const float* post_m_b  = (const float*)d_in[17];
  const float* post_s_W  = (const float*)d_in[18];
  const float* post_s_b  = (const float*)d_in[19];

  float* out    = (float*)d_out;
  float* states = out;                       // [100][512][200]
  float* pm     = out + 10240000;
  float* ps     = out + 11776000;
  float* qm     = out + 13312000;
  float* qs     = out + 14848000;

  u16* Epost = (u16*)d_ws;                               // 10,240,000 bf16 = 20.48 MB
  u16* wbuf  = (u16*)((char*)d_ws + 20480000);           // 1.21 MB packed weights

  hipLaunchKernelGGL(prep2, dim3((NFRAG + 255) / 256), dim3(256), 0, stream,
                     lat_act_W, gru_Wih, gru_Whh, post1_W, post_m_W, prior1_W, wbuf);

  hipLaunchKernelGGL(epost_kernel, dim3(800), dim3(256), 0, stream,
                     e, post1_b, wbuf, Epost);

  hipLaunchKernelGGL(core_kernel, dim3(32), dim3(512), 0, stream,
                     u, lat_act_b, gru_bih, gru_bhh, post_m_b, wbuf, Epost, states, qm);

  hipLaunchKernelGGL(phasec_kernel, dim3(1600), dim3(256), 0, stream,
                     states, Epost, wbuf, prior1_b,
                     prior_m_W, prior_m_b, prior_s_W, prior_s_b,
                     post_s_W, post_s_b, pm, ps, qs);
}